// Round 4
// baseline (563.906 us; speedup 1.0000x reference)
//
#include <hip/hip_runtime.h>
#include <math.h>

// ---------------------------------------------------------------------------
// PointsToImage: ball-query (K=32, R=0.1) -> PointNetConv msg=[x_j, pos_j-pos_dst]
// -> Linear(66,128) -> masked-BatchNorm -> ReLU -> Linear(128,64) -> scatter-max
// into pixel nodes, output [B=32, F=64, 32, 32] fp32.
//
// R4 restructure:
//  - k_stats ELIMINATED: BN stats decomposed by source node.
//    ballquery accumulates per-node {deg, Stx, Sty} (3 atomics/edge) and
//    per-query {Srx2, Srxry, Sry2} (wave-reduced, 3 atomics/query, 64 replicas).
//    k_y folds the node-level sums P=Σ(1+deg)y, Q=Σ(1+deg)y², R=Σy·B, S=Σy·C
//    (B=deg·px−Stx, C=deg·py−Sty) using exact fp32 y in registers.
//    k_finalize: Σz = P + uΣB + vΣC ; Σz² = Q + 2uR + 2vS + u²ΣD + 2uvΣE + v²ΣF.
//  - y stored bf16-packed (f, f+64) -> 1 dword gather per lane per edge.
//  - k_out: 2 queries/wave, grid 4096 (better occupancy/tail).
// Pipeline: k_prep -> k_ballquery -> k_y -> k_finalize -> k_self -> k_out
// ---------------------------------------------------------------------------

#define NPTS   32768
#define KNB    32
#define BN_EPS 1e-5f

// workspace layout (bytes)
#define WS_NBRS     0u           // int[NPTS*KNB]      = 4194304
#define WS_NBRCNT   4194304u     // int[NPTS]          = 131072
#define WS_DEG      4325376u     // float[NPTS]        = 131072
#define WS_STX      4456448u     // float[NPTS]        = 131072
#define WS_STY      4587520u     // float[NPTS]        = 131072
#define WS_DEFREP   4718592u     // float[64*4]        = 1024   (ΣD,ΣE,ΣF replicas)
#define WS_SCSH     4719616u     // float[256]         = 1024
#define WS_W2B      4720640u     // ushort[8192]       = 16384  (W2 in B-frag layout, bf16)
#define WS_PART     4737024u     // float[256*516]     = 528384 (k_y block partials)
#define WS_Y        5265408u     // ushort[NPTS*128]   = 8 MB   (bf16 pairs: lane -> (f=lane, f=lane+64))

typedef __attribute__((ext_vector_type(8))) short short8;
typedef __attribute__((ext_vector_type(4))) float floatx4;

__device__ __forceinline__ unsigned short f2bf(float f) {
    unsigned int u = __float_as_uint(f);
    unsigned int r = u + 0x7fffu + ((u >> 16) & 1u);   // RNE
    return (unsigned short)(r >> 16);
}
__device__ __forceinline__ float bf_lo(unsigned int w) { return __uint_as_float(w << 16); }
__device__ __forceinline__ float bf_hi(unsigned int w) { return __uint_as_float(w & 0xffff0000u); }

__device__ __forceinline__ void atomic_max_float(float* addr, float v) {
    if (v >= 0.0f) atomicMax((int*)addr, __float_as_int(v));
    else           atomicMin((unsigned int*)addr, __float_as_uint(v));
}

// ------------------- prep: zero aggregates, pack W2 into B-frag bf16 --------
__global__ void k_prep(const float* __restrict__ W2, unsigned short* __restrict__ w2b,
                       float* __restrict__ deg, float* __restrict__ stx,
                       float* __restrict__ sty, float* __restrict__ defrep) {
    int t = blockIdx.x * 256 + threadIdx.x;     // 128 blocks * 256 = 32768
    deg[t] = 0.0f; stx[t] = 0.0f; sty[t] = 0.0f;
    if (t < 256) defrep[t] = 0.0f;
    if (t < 8192) {
        int j  = t & 7;
        int L  = (t >> 3) & 63;
        int ks = (t >> 9) & 3;
        int t4 = t >> 11;
        int k = ks * 32 + (L >> 4) * 8 + j;
        int n = t4 * 16 + (L & 15);
        w2b[t] = f2bf(W2[k * 64 + n]);
    }
}

// --------------------------- ball query (wave per query, exact) -------------
__launch_bounds__(256)
__global__ void k_ballquery(const float* __restrict__ pos,
                            int* __restrict__ nbrs, int* __restrict__ nbr_cnt,
                            float* __restrict__ deg, float* __restrict__ stx,
                            float* __restrict__ sty, float* __restrict__ defrep) {
    __shared__ float cd2[4][256];
    __shared__ int   cidx[4][256];
    __shared__ int   cnt[4], ocnt[4];
    int tid = threadIdx.x, wave = tid >> 6, lane = tid & 63;
    int q = blockIdx.x * 4 + wave;
    int base = (q >> 10) << 10;
    float qx = pos[2 * q], qy = pos[2 * q + 1];
    int row = min(max((int)(qy * 32.0f), 0), 31);
    int col = min(max((int)(qx * 32.0f), 0), 31);
    int pixq = base + row * 32 + col;
    float tx = pos[2 * pixq], ty = pos[2 * pixq + 1];
    if (lane == 0) { cnt[wave] = 0; ocnt[wave] = 0; }
    __syncthreads();

    for (int j = lane; j < 1024; j += 64) {
        int g = base + j;
        float2 p = *(const float2*)&pos[2 * g];
        float dx = p.x - qx, dy = p.y - qy;
        float d2 = __fadd_rn(__fmul_rn(dx, dx), __fmul_rn(dy, dy)); // no FMA contraction
        if (d2 <= 0.01f) {
            int s = atomicAdd(&cnt[wave], 1);
            if (s < 256) { cd2[wave][s] = d2; cidx[wave][s] = g; }
        }
    }
    __syncthreads();
    int c = min(cnt[wave], 256);
    float aD = 0, aE = 0, aF = 0;
    for (int i = lane; i < c; i += 64) {
        float d2i = cd2[wave][i]; int gi = cidx[wave][i];
        int rank = 0;
        for (int t = 0; t < c; ++t) {
            float d2t = cd2[wave][t]; int gt = cidx[wave][t];
            rank += (d2t < d2i || (d2t == d2i && gt < gi)) ? 1 : 0;
        }
        if (rank < KNB && gi != pixq) {          // top-K, then remove_self_loops
            int s = atomicAdd(&ocnt[wave], 1);
            nbrs[q * KNB + s] = gi;
            float rx = pos[2 * gi] - tx, ry = pos[2 * gi + 1] - ty;
            aD += rx * rx; aE += rx * ry; aF += ry * ry;
            atomicAdd(&deg[gi], 1.0f);
            atomicAdd(&stx[gi], tx);
            atomicAdd(&sty[gi], ty);
        }
    }
    for (int o = 1; o < 64; o <<= 1) {
        aD += __shfl_xor(aD, o); aE += __shfl_xor(aE, o); aF += __shfl_xor(aF, o);
    }
    __syncthreads();
    if (lane == 0) {
        nbr_cnt[q] = ocnt[wave];
        int r = (q & 63) * 4;
        atomicAdd(&defrep[r + 0], aD);
        atomicAdd(&defrep[r + 1], aE);
        atomicAdd(&defrep[r + 2], aF);
    }
}

// ---------------- node GEMM1 + folded BN node-stats: y = x@W1[:64]+b1 -------
// grid 256 blocks, 128 nodes/block (wave: 4 iters x 8 nodes). y stored bf16.
__launch_bounds__(256)
__global__ void k_y(const float* __restrict__ x, const float* __restrict__ W1,
                    const float* __restrict__ b1, const float* __restrict__ pos,
                    const float* __restrict__ deg, const float* __restrict__ stxA,
                    const float* __restrict__ styA,
                    unsigned int* __restrict__ yb, float* __restrict__ partials) {
    __shared__ float w1s[64 * 128];
    __shared__ float stage[4][512];
    __shared__ float lsum[515];
    int tid = threadIdx.x;
    for (int i = tid; i < 64 * 128; i += 256) w1s[i] = W1[i];
    for (int i = tid; i < 515; i += 256) lsum[i] = 0.0f;
    __syncthreads();
    int wave = tid >> 6, lane = tid & 63;
    float b10 = b1[lane], b11 = b1[64 + lane];
    float* st = &stage[wave][0];
    float P0 = 0, Q0 = 0, R0 = 0, S0 = 0, P1 = 0, Q1 = 0, R1 = 0, S1 = 0;
    float sB = 0, sC = 0, sDeg = 0;

    for (int it = 0; it < 4; ++it) {
        int nbase = ((blockIdx.x * 4 + wave) * 4 + it) * 8;
        __builtin_amdgcn_wave_barrier();
#pragma unroll
        for (int mm = 0; mm < 8; ++mm)
            st[mm * 64 + lane] = x[(nbase + mm) * 64 + lane];
        __builtin_amdgcn_wave_barrier();
        float z0[8], z1[8];
#pragma unroll
        for (int mm = 0; mm < 8; ++mm) { z0[mm] = b10; z1[mm] = b11; }
        for (int k4 = 0; k4 < 16; ++k4) {
            float wa0 = w1s[(k4 * 4 + 0) * 128 + lane], wa1 = w1s[(k4 * 4 + 1) * 128 + lane];
            float wa2 = w1s[(k4 * 4 + 2) * 128 + lane], wa3 = w1s[(k4 * 4 + 3) * 128 + lane];
            float wb0 = w1s[(k4 * 4 + 0) * 128 + 64 + lane], wb1 = w1s[(k4 * 4 + 1) * 128 + 64 + lane];
            float wb2 = w1s[(k4 * 4 + 2) * 128 + 64 + lane], wb3 = w1s[(k4 * 4 + 3) * 128 + 64 + lane];
#pragma unroll
            for (int mm = 0; mm < 8; ++mm) {
                float4 mk = *(const float4*)&st[mm * 64 + k4 * 4];
                z0[mm] += mk.x * wa0 + mk.y * wa1 + mk.z * wa2 + mk.w * wa3;
                z1[mm] += mk.x * wb0 + mk.y * wb1 + mk.z * wb2 + mk.w * wb3;
            }
        }
#pragma unroll
        for (int mm = 0; mm < 8; ++mm) {
            int n = nbase + mm;
            float dg = deg[n];
            float wgt = 1.0f + dg;
            float Bn = dg * pos[2 * n]     - stxA[n];
            float Cn = dg * pos[2 * n + 1] - styA[n];
            float a = z0[mm], bq = z1[mm];
            P0 += wgt * a;  Q0 += wgt * a * a;  R0 += a * Bn;  S0 += a * Cn;
            P1 += wgt * bq; Q1 += wgt * bq * bq; R1 += bq * Bn; S1 += bq * Cn;
            sB += Bn; sC += Cn; sDeg += dg;
            yb[n * 64 + lane] = ((unsigned int)f2bf(bq) << 16) | (unsigned int)f2bf(a);
        }
    }
    atomicAdd(&lsum[lane], P0);        atomicAdd(&lsum[64 + lane], P1);
    atomicAdd(&lsum[128 + lane], Q0);  atomicAdd(&lsum[192 + lane], Q1);
    atomicAdd(&lsum[256 + lane], R0);  atomicAdd(&lsum[320 + lane], R1);
    atomicAdd(&lsum[384 + lane], S0);  atomicAdd(&lsum[448 + lane], S1);
    if (lane == 0) {
        atomicAdd(&lsum[512], sB);
        atomicAdd(&lsum[513], sC);
        atomicAdd(&lsum[514], sDeg);
    }
    __syncthreads();
    for (int i = tid; i < 515; i += 256) partials[blockIdx.x * 516 + i] = lsum[i];
}

// --------------------------- finalize BN scale/shift ------------------------
__global__ void k_finalize(const float* __restrict__ gamma, const float* __restrict__ beta,
                           const float* __restrict__ W1, const float* __restrict__ partials,
                           const float* __restrict__ defrep, float* __restrict__ scsh) {
    __shared__ float red[515];
    __shared__ float sDEF[3];
    int tid = threadIdx.x;    // 256
    for (int i = tid; i < 515; i += 256) {
        float s = 0;
        for (int b = 0; b < 256; ++b) s += partials[b * 516 + i];
        red[i] = s;
    }
    if (tid < 3) {
        float s = 0;
        for (int r = 0; r < 64; ++r) s += defrep[r * 4 + tid];
        sDEF[tid] = s;
    }
    __syncthreads();
    if (tid < 128) {
        int f = tid;
        float P = red[f], Q = red[128 + f], R = red[256 + f], S = red[384 + f];
        float SB = red[512], SC = red[513], SDeg = red[514];
        float u = W1[8192 + f], v = W1[8320 + f];
        float cntv = 32768.0f + SDeg;
        float mean = (P + u * SB + v * SC) / cntv;
        float E2 = (Q + 2.0f * u * R + 2.0f * v * S
                    + u * u * sDEF[0] + 2.0f * u * v * sDEF[1] + v * v * sDEF[2]) / cntv;
        float var = E2 - mean * mean;
        float sc = gamma[f] / sqrtf(var + BN_EPS);
        scsh[f] = sc;
        scsh[128 + f] = beta[f] - mean * sc;
    }
}

// --------------------------- self pass (MFMA, plain store = out init) -------
__launch_bounds__(256)
__global__ void k_self(const unsigned int* __restrict__ yb, const float* __restrict__ scsh,
                       const unsigned short* __restrict__ w2b, const float* __restrict__ b2,
                       float* __restrict__ out) {
    __shared__ unsigned short hbuf[4][16 * 136];   // 272 B row stride
    int tid = threadIdx.x, wave = tid >> 6, lane = tid & 63;
    unsigned short* hb = hbuf[wave];
    short8 bfrag[4][4];
#pragma unroll
    for (int t = 0; t < 4; ++t)
#pragma unroll
        for (int ks = 0; ks < 4; ++ks)
            bfrag[t][ks] = *(const short8*)&w2b[((t * 4 + ks) * 64 + lane) * 8];
    float sc0 = scsh[lane],      sh0 = scsh[128 + lane];
    float sc1 = scsh[64 + lane], sh1 = scsh[192 + lane];
    float b2v0 = b2[(lane & 15)],      b2v1 = b2[16 + (lane & 15)];
    float b2v2 = b2[32 + (lane & 15)], b2v3 = b2[48 + (lane & 15)];

    int nbase = (blockIdx.x * 4 + wave) * 16;
#pragma unroll
    for (int c = 0; c < 2; ++c) {
        unsigned int yw[8];
#pragma unroll
        for (int j = 0; j < 8; ++j)
            yw[j] = yb[(nbase + c * 8 + j) * 64 + lane];
#pragma unroll
        for (int j = 0; j < 8; ++j) {
            int e = c * 8 + j;
            hb[e * 136 + lane]      = f2bf(fmaxf(bf_lo(yw[j]) * sc0 + sh0, 0.0f));
            hb[e * 136 + 64 + lane] = f2bf(fmaxf(bf_hi(yw[j]) * sc1 + sh1, 0.0f));
        }
    }
    __builtin_amdgcn_wave_barrier();
    floatx4 acc0 = {0,0,0,0}, acc1 = {0,0,0,0}, acc2 = {0,0,0,0}, acc3 = {0,0,0,0};
#pragma unroll
    for (int ks = 0; ks < 4; ++ks) {
        short8 a = *(const short8*)&hb[(lane & 15) * 136 + ks * 32 + (lane >> 4) * 8];
        acc0 = __builtin_amdgcn_mfma_f32_16x16x32_bf16(a, bfrag[0][ks], acc0, 0, 0, 0);
        acc1 = __builtin_amdgcn_mfma_f32_16x16x32_bf16(a, bfrag[1][ks], acc1, 0, 0, 0);
        acc2 = __builtin_amdgcn_mfma_f32_16x16x32_bf16(a, bfrag[2][ks], acc2, 0, 0, 0);
        acc3 = __builtin_amdgcn_mfma_f32_16x16x32_bf16(a, bfrag[3][ks], acc3, 0, 0, 0);
    }
    int nrow = nbase + (lane >> 4) * 4;
#pragma unroll
    for (int r = 0; r < 4; ++r) {
        int n = nrow + r;
        int obase = (n >> 10) * 65536 + (n & 1023);
        out[obase + ((lane & 15)) * 1024]      = acc0[r] + b2v0;
        out[obase + (16 + (lane & 15)) * 1024] = acc1[r] + b2v1;
        out[obase + (32 + (lane & 15)) * 1024] = acc2[r] + b2v2;
        out[obase + (48 + (lane & 15)) * 1024] = acc3[r] + b2v3;
    }
}

// --------------------------- neighbor pass (MFMA + atomic max) --------------
// wave handles 2 queries; grid 4096 blocks. bf16 y gather (1 dword/lane/edge).
__launch_bounds__(256)
__global__ void k_out(const unsigned int* __restrict__ yb, const float* __restrict__ pos,
                      const float* __restrict__ W1, const float* __restrict__ scsh,
                      const unsigned short* __restrict__ w2b, const float* __restrict__ b2,
                      const int* __restrict__ nbrs, const int* __restrict__ nbr_cnt,
                      float* __restrict__ out) {
    __shared__ unsigned short hbuf[4][16 * 136];
    int tid = threadIdx.x, wave = tid >> 6, lane = tid & 63;
    unsigned short* hb = hbuf[wave];
    short8 bfrag[4][4];
#pragma unroll
    for (int t = 0; t < 4; ++t)
#pragma unroll
        for (int ks = 0; ks < 4; ++ks)
            bfrag[t][ks] = *(const short8*)&w2b[((t * 4 + ks) * 64 + lane) * 8];
    float sc0 = scsh[lane],      sh0 = scsh[128 + lane];
    float sc1 = scsh[64 + lane], sh1 = scsh[192 + lane];
    float u0 = W1[8192 + lane], v0 = W1[8320 + lane];
    float u1 = W1[8256 + lane], v1 = W1[8384 + lane];
    float b2l = b2[lane];
    int wid = blockIdx.x * 4 + wave;     // 16384 waves, 2 queries each

    for (int qi = 0; qi < 2; ++qi) {
        int q = wid * 2 + qi;
        int m = nbr_cnt[q];
        if (m == 0) continue;
        int b = q >> 10;
        float qx = pos[2 * q], qy = pos[2 * q + 1];
        int row = min(max((int)(qy * 32.0f), 0), 31);
        int col = min(max((int)(qx * 32.0f), 0), 31);
        int pixq = (b << 10) + row * 32 + col;
        float tx = pos[2 * pixq], ty = pos[2 * pixq + 1];
        int nv = (lane < m) ? nbrs[q * KNB + lane] : q;
        float px = pos[2 * nv], py = pos[2 * nv + 1];
        floatx4 om0 = {-INFINITY,-INFINITY,-INFINITY,-INFINITY};
        floatx4 om1 = om0, om2 = om0, om3 = om0;
        int ntile = (m + 15) >> 4;
        for (int mt = 0; mt < ntile; ++mt) {
#pragma unroll
            for (int c = 0; c < 2; ++c) {
                unsigned int yw[8]; float rxx[8], ryy[8];
#pragma unroll
                for (int j = 0; j < 8; ++j) {
                    int e = mt * 16 + c * 8 + j;
                    if (e < m) {
                        int src = __shfl(nv, e);
                        rxx[j] = __shfl(px, e) - tx;
                        ryy[j] = __shfl(py, e) - ty;
                        yw[j] = yb[src * 64 + lane];
                    } else {
                        rxx[j] = 0.0f; ryy[j] = 0.0f; yw[j] = 0u;
                    }
                }
#pragma unroll
                for (int j = 0; j < 8; ++j) {
                    int e16 = c * 8 + j;
                    float z0 = bf_lo(yw[j]) + rxx[j] * u0 + ryy[j] * v0;
                    float z1 = bf_hi(yw[j]) + rxx[j] * u1 + ryy[j] * v1;
                    hb[e16 * 136 + lane]      = f2bf(fmaxf(z0 * sc0 + sh0, 0.0f));
                    hb[e16 * 136 + 64 + lane] = f2bf(fmaxf(z1 * sc1 + sh1, 0.0f));
                }
            }
            __builtin_amdgcn_wave_barrier();
            floatx4 acc0 = {0,0,0,0}, acc1 = {0,0,0,0}, acc2 = {0,0,0,0}, acc3 = {0,0,0,0};
#pragma unroll
            for (int ks = 0; ks < 4; ++ks) {
                short8 a = *(const short8*)&hb[(lane & 15) * 136 + ks * 32 + (lane >> 4) * 8];
                acc0 = __builtin_amdgcn_mfma_f32_16x16x32_bf16(a, bfrag[0][ks], acc0, 0, 0, 0);
                acc1 = __builtin_amdgcn_mfma_f32_16x16x32_bf16(a, bfrag[1][ks], acc1, 0, 0, 0);
                acc2 = __builtin_amdgcn_mfma_f32_16x16x32_bf16(a, bfrag[2][ks], acc2, 0, 0, 0);
                acc3 = __builtin_amdgcn_mfma_f32_16x16x32_bf16(a, bfrag[3][ks], acc3, 0, 0, 0);
            }
            __builtin_amdgcn_wave_barrier();
#pragma unroll
            for (int r = 0; r < 4; ++r) {
                int e = mt * 16 + (lane >> 4) * 4 + r;
                if (e < m) {
                    om0[r] = fmaxf(om0[r], acc0[r]);
                    om1[r] = fmaxf(om1[r], acc1[r]);
                    om2[r] = fmaxf(om2[r], acc2[r]);
                    om3[r] = fmaxf(om3[r], acc3[r]);
                }
            }
        }
        float w0 = fmaxf(fmaxf(om0[0], om0[1]), fmaxf(om0[2], om0[3]));
        float w1 = fmaxf(fmaxf(om1[0], om1[1]), fmaxf(om1[2], om1[3]));
        float w2 = fmaxf(fmaxf(om2[0], om2[1]), fmaxf(om2[2], om2[3]));
        float w3 = fmaxf(fmaxf(om3[0], om3[1]), fmaxf(om3[2], om3[3]));
        w0 = fmaxf(w0, __shfl_xor(w0, 16)); w0 = fmaxf(w0, __shfl_xor(w0, 32));
        w1 = fmaxf(w1, __shfl_xor(w1, 16)); w1 = fmaxf(w1, __shfl_xor(w1, 32));
        w2 = fmaxf(w2, __shfl_xor(w2, 16)); w2 = fmaxf(w2, __shfl_xor(w2, 32));
        w3 = fmaxf(w3, __shfl_xor(w3, 16)); w3 = fmaxf(w3, __shfl_xor(w3, 32));
        int g = lane >> 4;   // feature = g*16 + (lane&15) = lane
        float vf = (g == 0) ? w0 : (g == 1) ? w1 : (g == 2) ? w2 : w3;
        vf += b2l;
        atomic_max_float(&out[b * 65536 + lane * 1024 + (pixq & 1023)], vf);
    }
}

extern "C" void kernel_launch(void* const* d_in, const int* in_sizes, int n_in,
                              void* d_out, int out_size, void* d_ws, size_t ws_size,
                              hipStream_t stream) {
    const float* x     = (const float*)d_in[0];
    const float* pos   = (const float*)d_in[1];
    // d_in[2] = batch (unused: points are sorted, b = idx >> 10)
    const float* W1    = (const float*)d_in[3];
    const float* b1    = (const float*)d_in[4];
    const float* gamma = (const float*)d_in[5];
    const float* beta  = (const float*)d_in[6];
    const float* W2    = (const float*)d_in[7];
    const float* b2    = (const float*)d_in[8];
    float* out = (float*)d_out;
    char* ws = (char*)d_ws;
    int*   nbrs     = (int*)(ws + WS_NBRS);
    int*   nbr_cnt  = (int*)(ws + WS_NBRCNT);
    float* deg      = (float*)(ws + WS_DEG);
    float* stx      = (float*)(ws + WS_STX);
    float* sty      = (float*)(ws + WS_STY);
    float* defrep   = (float*)(ws + WS_DEFREP);
    float* scsh     = (float*)(ws + WS_SCSH);
    unsigned short* w2b = (unsigned short*)(ws + WS_W2B);
    float* partials = (float*)(ws + WS_PART);
    unsigned int* yb = (unsigned int*)(ws + WS_Y);

    k_prep<<<128, 256, 0, stream>>>(W2, w2b, deg, stx, sty, defrep);
    k_ballquery<<<NPTS / 4, 256, 0, stream>>>(pos, nbrs, nbr_cnt, deg, stx, sty, defrep);
    k_y<<<256, 256, 0, stream>>>(x, W1, b1, pos, deg, stx, sty, yb, partials);
    k_finalize<<<1, 256, 0, stream>>>(gamma, beta, W1, partials, defrep, scsh);
    k_self<<<NPTS / 64, 256, 0, stream>>>(yb, scsh, w2b, b2, out);
    k_out<<<NPTS / 8, 256, 0, stream>>>(yb, pos, W1, scsh, w2b, b2, nbrs, nbr_cnt, out);
}

// Round 5
// 335.713 us; speedup vs baseline: 1.6797x; 1.6797x over previous
//
#include <hip/hip_runtime.h>
#include <math.h>

// ---------------------------------------------------------------------------
// PointsToImage: ball-query (K=32, R=0.1) -> PointNetConv msg=[x_j, pos_j-pos_dst]
// -> Linear(66,128) -> masked-BatchNorm -> ReLU -> Linear(128,64) -> scatter-max
// into pixel nodes, output [B=32, F=64, 32, 32] fp32.
//
// R5: R4's per-edge GLOBAL atomics (deg/stx/sty) wrote through L2 to HBM
// (WRITE_SIZE 86 MB = 2.76M x 32B) and stalled ballquery at 300 us.
// Now: sample-resident ballquery blocks (32 samples x 16 chunks x 64 queries),
// pos in LDS + distance partners in registers, node aggregates in LDS with
// per-chunk plain stores, k_nodeagg sums the 16 chunk partials. Zero edge atomics.
// Pipeline: k_prep -> k_ballquery -> k_nodeagg -> k_y -> k_finalize -> k_self -> k_out
// ---------------------------------------------------------------------------

#define NPTS   32768
#define KNB    32
#define BN_EPS 1e-5f

// workspace layout (bytes)
#define WS_NBRS     0u           // int[NPTS*KNB]      = 4194304
#define WS_NBRCNT   4194304u     // int[NPTS]          = 131072
#define WS_DEG      4325376u     // float[NPTS]        = 131072
#define WS_STX      4456448u     // float[NPTS]        = 131072
#define WS_STY      4587520u     // float[NPTS]        = 131072
#define WS_DEFREP   4718592u     // float[64*4]        = 1024   (SD,SE,SF replicas)
#define WS_SCSH     4719616u     // float[256]         = 1024
#define WS_W2B      4720640u     // ushort[8192]       = 16384  (W2 in B-frag layout, bf16)
#define WS_PART     4737024u     // float[256*516]     = 528384 (k_y block partials)
#define WS_Y        5265408u     // uint[NPTS*64]      = 8 MB   (bf16 pairs: lane -> (f, f+64))
#define WS_BQPART   13654016u    // float[512*3072]    = 6291456 (ballquery chunk partials)

typedef __attribute__((ext_vector_type(8))) short short8;
typedef __attribute__((ext_vector_type(4))) float floatx4;

__device__ __forceinline__ unsigned short f2bf(float f) {
    unsigned int u = __float_as_uint(f);
    unsigned int r = u + 0x7fffu + ((u >> 16) & 1u);   // RNE
    return (unsigned short)(r >> 16);
}
__device__ __forceinline__ float bf_lo(unsigned int w) { return __uint_as_float(w << 16); }
__device__ __forceinline__ float bf_hi(unsigned int w) { return __uint_as_float(w & 0xffff0000u); }

__device__ __forceinline__ void atomic_max_float(float* addr, float v) {
    if (v >= 0.0f) atomicMax((int*)addr, __float_as_int(v));
    else           atomicMin((unsigned int*)addr, __float_as_uint(v));
}

// ------------------- prep: zero defrep, pack W2 into B-frag bf16 ------------
__global__ void k_prep(const float* __restrict__ W2, unsigned short* __restrict__ w2b,
                       float* __restrict__ defrep) {
    int t = blockIdx.x * 256 + threadIdx.x;     // 32 blocks * 256 = 8192
    if (t < 256) defrep[t] = 0.0f;
    if (t < 8192) {
        int j  = t & 7;
        int L  = (t >> 3) & 63;
        int ks = (t >> 9) & 3;
        int t4 = t >> 11;
        int k = ks * 32 + (L >> 4) * 8 + j;
        int n = t4 * 16 + (L & 15);
        w2b[t] = f2bf(W2[k * 64 + n]);
    }
}

// --------------------------- ball query (sample-resident, atomic-free) ------
// 512 blocks = 32 samples x 16 chunks; block handles 64 queries (wave: 16).
// Exact K-smallest-within-radius, (d2,idx) tie-break via packed u64 keys.
// d2 arithmetic matches reference bit-exactly (unfused fp32 mul/add).
__launch_bounds__(256)
__global__ void k_ballquery(const float* __restrict__ pos,
                            int* __restrict__ nbrs, int* __restrict__ nbr_cnt,
                            float* __restrict__ bqpart, float* __restrict__ defrep) {
    __shared__ float2 poss[1024];
    __shared__ float accd[1024], accx[1024], accy[1024];
    __shared__ unsigned long long cand[4][256];
    __shared__ int cnt[4], ocnt[4];
    int tid = threadIdx.x, wave = tid >> 6, lane = tid & 63;
    int s = blockIdx.x >> 4;           // sample
    int chunk = blockIdx.x & 15;       // 16 chunks of 64 queries
    int base = s << 10;
    for (int i = tid; i < 1024; i += 256) poss[i] = *(const float2*)&pos[2 * (base + i)];
    for (int i = tid; i < 1024; i += 256) { accd[i] = 0.0f; accx[i] = 0.0f; accy[i] = 0.0f; }
    __syncthreads();
    // distance partners held in registers: lane owns points j = k*64+lane
    float2 pr[16];
#pragma unroll
    for (int k = 0; k < 16; ++k) pr[k] = poss[k * 64 + lane];

    float aD = 0, aE = 0, aF = 0;
    for (int qi = 0; qi < 16; ++qi) {
        int ql = chunk * 64 + wave * 16 + qi;
        int q = base + ql;
        float2 qp = poss[ql];
        int row = min(max((int)(qp.y * 32.0f), 0), 31);
        int col = min(max((int)(qp.x * 32.0f), 0), 31);
        int pixl = row * 32 + col;
        float2 tp = poss[pixl];
        if (lane == 0) { cnt[wave] = 0; ocnt[wave] = 0; }
        __builtin_amdgcn_wave_barrier();
#pragma unroll
        for (int k = 0; k < 16; ++k) {
            float dx = pr[k].x - qp.x, dy = pr[k].y - qp.y;
            float d2 = __fadd_rn(__fmul_rn(dx, dx), __fmul_rn(dy, dy)); // no FMA contraction
            if (d2 <= 0.01f) {
                int sl = atomicAdd(&cnt[wave], 1);
                if (sl < 256)
                    cand[wave][sl] = ((unsigned long long)__float_as_uint(d2) << 32)
                                     | (unsigned int)(k * 64 + lane);
            }
        }
        __builtin_amdgcn_wave_barrier();
        int c = min(cnt[wave], 256);
        for (int i = lane; i < c; i += 64) {
            unsigned long long key = cand[wave][i];
            int rank = 0;
            for (int t = 0; t < c; ++t) rank += (cand[wave][t] < key) ? 1 : 0;
            int j = (int)(key & 0xffffffffu);
            if (rank < KNB && j != pixl) {         // top-K, then remove_self_loops
                int sl = atomicAdd(&ocnt[wave], 1);
                nbrs[q * KNB + sl] = base + j;
                float rx = poss[j].x - tp.x, ry = poss[j].y - tp.y;
                aD += rx * rx; aE += rx * ry; aF += ry * ry;
                atomicAdd(&accd[j], 1.0f);
                atomicAdd(&accx[j], tp.x);
                atomicAdd(&accy[j], tp.y);
            }
        }
        __builtin_amdgcn_wave_barrier();
        if (lane == 0) nbr_cnt[q] = ocnt[wave];
    }
#pragma unroll
    for (int o = 1; o < 64; o <<= 1) {
        aD += __shfl_xor(aD, o); aE += __shfl_xor(aE, o); aF += __shfl_xor(aF, o);
    }
    __syncthreads();
    float* pb = &bqpart[blockIdx.x * 3072];
    for (int i = tid; i < 1024; i += 256) {
        pb[i] = accd[i]; pb[1024 + i] = accx[i]; pb[2048 + i] = accy[i];
    }
    if (tid == 0) {
        int r = (blockIdx.x & 63) * 4;
        atomicAdd(&defrep[r + 0], aD);
        atomicAdd(&defrep[r + 1], aE);
        atomicAdd(&defrep[r + 2], aF);
    }
}

// ------------------- sum the 16 chunk partials per node ---------------------
__global__ void k_nodeagg(const float* __restrict__ bqpart, float* __restrict__ deg,
                          float* __restrict__ stx, float* __restrict__ sty) {
    int t = blockIdx.x * 256 + threadIdx.x;   // 128 blocks -> 32768
    int s = t >> 10, off = t & 1023;
    const float* pb = &bqpart[(s * 16) * 3072];
    float d = 0, xx = 0, yy = 0;
    for (int j = 0; j < 16; ++j) {
        d  += pb[j * 3072 + off];
        xx += pb[j * 3072 + 1024 + off];
        yy += pb[j * 3072 + 2048 + off];
    }
    deg[t] = d; stx[t] = xx; sty[t] = yy;
}

// ---------------- node GEMM1 + folded BN node-stats: y = x@W1[:64]+b1 -------
__launch_bounds__(256)
__global__ void k_y(const float* __restrict__ x, const float* __restrict__ W1,
                    const float* __restrict__ b1, const float* __restrict__ pos,
                    const float* __restrict__ deg, const float* __restrict__ stxA,
                    const float* __restrict__ styA,
                    unsigned int* __restrict__ yb, float* __restrict__ partials) {
    __shared__ float w1s[64 * 128];
    __shared__ float stage[4][512];
    __shared__ float lsum[515];
    int tid = threadIdx.x;
    for (int i = tid; i < 64 * 128; i += 256) w1s[i] = W1[i];
    for (int i = tid; i < 515; i += 256) lsum[i] = 0.0f;
    __syncthreads();
    int wave = tid >> 6, lane = tid & 63;
    float b10 = b1[lane], b11 = b1[64 + lane];
    float* st = &stage[wave][0];
    float P0 = 0, Q0 = 0, R0 = 0, S0 = 0, P1 = 0, Q1 = 0, R1 = 0, S1 = 0;
    float sB = 0, sC = 0, sDeg = 0;

    for (int it = 0; it < 4; ++it) {
        int nbase = ((blockIdx.x * 4 + wave) * 4 + it) * 8;
        __builtin_amdgcn_wave_barrier();
#pragma unroll
        for (int mm = 0; mm < 8; ++mm)
            st[mm * 64 + lane] = x[(nbase + mm) * 64 + lane];
        __builtin_amdgcn_wave_barrier();
        float z0[8], z1[8];
#pragma unroll
        for (int mm = 0; mm < 8; ++mm) { z0[mm] = b10; z1[mm] = b11; }
        for (int k4 = 0; k4 < 16; ++k4) {
            float wa0 = w1s[(k4 * 4 + 0) * 128 + lane], wa1 = w1s[(k4 * 4 + 1) * 128 + lane];
            float wa2 = w1s[(k4 * 4 + 2) * 128 + lane], wa3 = w1s[(k4 * 4 + 3) * 128 + lane];
            float wb0 = w1s[(k4 * 4 + 0) * 128 + 64 + lane], wb1 = w1s[(k4 * 4 + 1) * 128 + 64 + lane];
            float wb2 = w1s[(k4 * 4 + 2) * 128 + 64 + lane], wb3 = w1s[(k4 * 4 + 3) * 128 + 64 + lane];
#pragma unroll
            for (int mm = 0; mm < 8; ++mm) {
                float4 mk = *(const float4*)&st[mm * 64 + k4 * 4];
                z0[mm] += mk.x * wa0 + mk.y * wa1 + mk.z * wa2 + mk.w * wa3;
                z1[mm] += mk.x * wb0 + mk.y * wb1 + mk.z * wb2 + mk.w * wb3;
            }
        }
#pragma unroll
        for (int mm = 0; mm < 8; ++mm) {
            int n = nbase + mm;
            float dg = deg[n];
            float wgt = 1.0f + dg;
            float Bn = dg * pos[2 * n]     - stxA[n];
            float Cn = dg * pos[2 * n + 1] - styA[n];
            float a = z0[mm], bq = z1[mm];
            P0 += wgt * a;  Q0 += wgt * a * a;  R0 += a * Bn;  S0 += a * Cn;
            P1 += wgt * bq; Q1 += wgt * bq * bq; R1 += bq * Bn; S1 += bq * Cn;
            sB += Bn; sC += Cn; sDeg += dg;
            yb[n * 64 + lane] = ((unsigned int)f2bf(bq) << 16) | (unsigned int)f2bf(a);
        }
    }
    atomicAdd(&lsum[lane], P0);        atomicAdd(&lsum[64 + lane], P1);
    atomicAdd(&lsum[128 + lane], Q0);  atomicAdd(&lsum[192 + lane], Q1);
    atomicAdd(&lsum[256 + lane], R0);  atomicAdd(&lsum[320 + lane], R1);
    atomicAdd(&lsum[384 + lane], S0);  atomicAdd(&lsum[448 + lane], S1);
    if (lane == 0) {
        atomicAdd(&lsum[512], sB);
        atomicAdd(&lsum[513], sC);
        atomicAdd(&lsum[514], sDeg);
    }
    __syncthreads();
    for (int i = tid; i < 515; i += 256) partials[blockIdx.x * 516 + i] = lsum[i];
}

// --------------------------- finalize BN scale/shift ------------------------
__global__ void k_finalize(const float* __restrict__ gamma, const float* __restrict__ beta,
                           const float* __restrict__ W1, const float* __restrict__ partials,
                           const float* __restrict__ defrep, float* __restrict__ scsh) {
    __shared__ float red[515];
    __shared__ float sDEF[3];
    int tid = threadIdx.x;    // 256
    for (int i = tid; i < 515; i += 256) {
        float s = 0;
        for (int b = 0; b < 256; ++b) s += partials[b * 516 + i];
        red[i] = s;
    }
    if (tid < 3) {
        float s = 0;
        for (int r = 0; r < 64; ++r) s += defrep[r * 4 + tid];
        sDEF[tid] = s;
    }
    __syncthreads();
    if (tid < 128) {
        int f = tid;
        float P = red[f], Q = red[128 + f], R = red[256 + f], S = red[384 + f];
        float SB = red[512], SC = red[513], SDeg = red[514];
        float u = W1[8192 + f], v = W1[8320 + f];
        float cntv = 32768.0f + SDeg;
        float mean = (P + u * SB + v * SC) / cntv;
        float E2 = (Q + 2.0f * u * R + 2.0f * v * S
                    + u * u * sDEF[0] + 2.0f * u * v * sDEF[1] + v * v * sDEF[2]) / cntv;
        float var = E2 - mean * mean;
        float sc = gamma[f] / sqrtf(var + BN_EPS);
        scsh[f] = sc;
        scsh[128 + f] = beta[f] - mean * sc;
    }
}

// --------------------------- self pass (MFMA, plain store = out init) -------
__launch_bounds__(256)
__global__ void k_self(const unsigned int* __restrict__ yb, const float* __restrict__ scsh,
                       const unsigned short* __restrict__ w2b, const float* __restrict__ b2,
                       float* __restrict__ out) {
    __shared__ unsigned short hbuf[4][16 * 136];   // 272 B row stride
    int tid = threadIdx.x, wave = tid >> 6, lane = tid & 63;
    unsigned short* hb = hbuf[wave];
    short8 bfrag[4][4];
#pragma unroll
    for (int t = 0; t < 4; ++t)
#pragma unroll
        for (int ks = 0; ks < 4; ++ks)
            bfrag[t][ks] = *(const short8*)&w2b[((t * 4 + ks) * 64 + lane) * 8];
    float sc0 = scsh[lane],      sh0 = scsh[128 + lane];
    float sc1 = scsh[64 + lane], sh1 = scsh[192 + lane];
    float b2v0 = b2[(lane & 15)],      b2v1 = b2[16 + (lane & 15)];
    float b2v2 = b2[32 + (lane & 15)], b2v3 = b2[48 + (lane & 15)];

    int nbase = (blockIdx.x * 4 + wave) * 16;
#pragma unroll
    for (int c = 0; c < 2; ++c) {
        unsigned int yw[8];
#pragma unroll
        for (int j = 0; j < 8; ++j)
            yw[j] = yb[(nbase + c * 8 + j) * 64 + lane];
#pragma unroll
        for (int j = 0; j < 8; ++j) {
            int e = c * 8 + j;
            hb[e * 136 + lane]      = f2bf(fmaxf(bf_lo(yw[j]) * sc0 + sh0, 0.0f));
            hb[e * 136 + 64 + lane] = f2bf(fmaxf(bf_hi(yw[j]) * sc1 + sh1, 0.0f));
        }
    }
    __builtin_amdgcn_wave_barrier();
    floatx4 acc0 = {0,0,0,0}, acc1 = {0,0,0,0}, acc2 = {0,0,0,0}, acc3 = {0,0,0,0};
#pragma unroll
    for (int ks = 0; ks < 4; ++ks) {
        short8 a = *(const short8*)&hb[(lane & 15) * 136 + ks * 32 + (lane >> 4) * 8];
        acc0 = __builtin_amdgcn_mfma_f32_16x16x32_bf16(a, bfrag[0][ks], acc0, 0, 0, 0);
        acc1 = __builtin_amdgcn_mfma_f32_16x16x32_bf16(a, bfrag[1][ks], acc1, 0, 0, 0);
        acc2 = __builtin_amdgcn_mfma_f32_16x16x32_bf16(a, bfrag[2][ks], acc2, 0, 0, 0);
        acc3 = __builtin_amdgcn_mfma_f32_16x16x32_bf16(a, bfrag[3][ks], acc3, 0, 0, 0);
    }
    int nrow = nbase + (lane >> 4) * 4;
#pragma unroll
    for (int r = 0; r < 4; ++r) {
        int n = nrow + r;
        int obase = (n >> 10) * 65536 + (n & 1023);
        out[obase + ((lane & 15)) * 1024]      = acc0[r] + b2v0;
        out[obase + (16 + (lane & 15)) * 1024] = acc1[r] + b2v1;
        out[obase + (32 + (lane & 15)) * 1024] = acc2[r] + b2v2;
        out[obase + (48 + (lane & 15)) * 1024] = acc3[r] + b2v3;
    }
}

// --------------------------- neighbor pass (MFMA + atomic max) --------------
__launch_bounds__(256)
__global__ void k_out(const unsigned int* __restrict__ yb, const float* __restrict__ pos,
                      const float* __restrict__ W1, const float* __restrict__ scsh,
                      const unsigned short* __restrict__ w2b, const float* __restrict__ b2,
                      const int* __restrict__ nbrs, const int* __restrict__ nbr_cnt,
                      float* __restrict__ out) {
    __shared__ unsigned short hbuf[4][16 * 136];
    int tid = threadIdx.x, wave = tid >> 6, lane = tid & 63;
    unsigned short* hb = hbuf[wave];
    short8 bfrag[4][4];
#pragma unroll
    for (int t = 0; t < 4; ++t)
#pragma unroll
        for (int ks = 0; ks < 4; ++ks)
            bfrag[t][ks] = *(const short8*)&w2b[((t * 4 + ks) * 64 + lane) * 8];
    float sc0 = scsh[lane],      sh0 = scsh[128 + lane];
    float sc1 = scsh[64 + lane], sh1 = scsh[192 + lane];
    float u0 = W1[8192 + lane], v0 = W1[8320 + lane];
    float u1 = W1[8256 + lane], v1 = W1[8384 + lane];
    float b2l = b2[lane];
    int wid = blockIdx.x * 4 + wave;     // 16384 waves, 2 queries each

    for (int qi = 0; qi < 2; ++qi) {
        int q = wid * 2 + qi;
        int m = nbr_cnt[q];
        if (m == 0) continue;
        int b = q >> 10;
        float qx = pos[2 * q], qy = pos[2 * q + 1];
        int row = min(max((int)(qy * 32.0f), 0), 31);
        int col = min(max((int)(qx * 32.0f), 0), 31);
        int pixq = (b << 10) + row * 32 + col;
        float tx = pos[2 * pixq], ty = pos[2 * pixq + 1];
        int nv = (lane < m) ? nbrs[q * KNB + lane] : q;
        float px = pos[2 * nv], py = pos[2 * nv + 1];
        floatx4 om0 = {-INFINITY,-INFINITY,-INFINITY,-INFINITY};
        floatx4 om1 = om0, om2 = om0, om3 = om0;
        int ntile = (m + 15) >> 4;
        for (int mt = 0; mt < ntile; ++mt) {
#pragma unroll
            for (int c = 0; c < 2; ++c) {
                unsigned int yw[8]; float rxx[8], ryy[8];
#pragma unroll
                for (int j = 0; j < 8; ++j) {
                    int e = mt * 16 + c * 8 + j;
                    if (e < m) {
                        int src = __shfl(nv, e);
                        rxx[j] = __shfl(px, e) - tx;
                        ryy[j] = __shfl(py, e) - ty;
                        yw[j] = yb[src * 64 + lane];
                    } else {
                        rxx[j] = 0.0f; ryy[j] = 0.0f; yw[j] = 0u;
                    }
                }
#pragma unroll
                for (int j = 0; j < 8; ++j) {
                    int e16 = c * 8 + j;
                    float z0 = bf_lo(yw[j]) + rxx[j] * u0 + ryy[j] * v0;
                    float z1 = bf_hi(yw[j]) + rxx[j] * u1 + ryy[j] * v1;
                    hb[e16 * 136 + lane]      = f2bf(fmaxf(z0 * sc0 + sh0, 0.0f));
                    hb[e16 * 136 + 64 + lane] = f2bf(fmaxf(z1 * sc1 + sh1, 0.0f));
                }
            }
            __builtin_amdgcn_wave_barrier();
            floatx4 acc0 = {0,0,0,0}, acc1 = {0,0,0,0}, acc2 = {0,0,0,0}, acc3 = {0,0,0,0};
#pragma unroll
            for (int ks = 0; ks < 4; ++ks) {
                short8 a = *(const short8*)&hb[(lane & 15) * 136 + ks * 32 + (lane >> 4) * 8];
                acc0 = __builtin_amdgcn_mfma_f32_16x16x32_bf16(a, bfrag[0][ks], acc0, 0, 0, 0);
                acc1 = __builtin_amdgcn_mfma_f32_16x16x32_bf16(a, bfrag[1][ks], acc1, 0, 0, 0);
                acc2 = __builtin_amdgcn_mfma_f32_16x16x32_bf16(a, bfrag[2][ks], acc2, 0, 0, 0);
                acc3 = __builtin_amdgcn_mfma_f32_16x16x32_bf16(a, bfrag[3][ks], acc3, 0, 0, 0);
            }
            __builtin_amdgcn_wave_barrier();
#pragma unroll
            for (int r = 0; r < 4; ++r) {
                int e = mt * 16 + (lane >> 4) * 4 + r;
                if (e < m) {
                    om0[r] = fmaxf(om0[r], acc0[r]);
                    om1[r] = fmaxf(om1[r], acc1[r]);
                    om2[r] = fmaxf(om2[r], acc2[r]);
                    om3[r] = fmaxf(om3[r], acc3[r]);
                }
            }
        }
        float w0 = fmaxf(fmaxf(om0[0], om0[1]), fmaxf(om0[2], om0[3]));
        float w1 = fmaxf(fmaxf(om1[0], om1[1]), fmaxf(om1[2], om1[3]));
        float w2 = fmaxf(fmaxf(om2[0], om2[1]), fmaxf(om2[2], om2[3]));
        float w3 = fmaxf(fmaxf(om3[0], om3[1]), fmaxf(om3[2], om3[3]));
        w0 = fmaxf(w0, __shfl_xor(w0, 16)); w0 = fmaxf(w0, __shfl_xor(w0, 32));
        w1 = fmaxf(w1, __shfl_xor(w1, 16)); w1 = fmaxf(w1, __shfl_xor(w1, 32));
        w2 = fmaxf(w2, __shfl_xor(w2, 16)); w2 = fmaxf(w2, __shfl_xor(w2, 32));
        w3 = fmaxf(w3, __shfl_xor(w3, 16)); w3 = fmaxf(w3, __shfl_xor(w3, 32));
        int g = lane >> 4;   // feature = g*16 + (lane&15) = lane
        float vf = (g == 0) ? w0 : (g == 1) ? w1 : (g == 2) ? w2 : w3;
        vf += b2l;
        atomic_max_float(&out[b * 65536 + lane * 1024 + (pixq & 1023)], vf);
    }
}

extern "C" void kernel_launch(void* const* d_in, const int* in_sizes, int n_in,
                              void* d_out, int out_size, void* d_ws, size_t ws_size,
                              hipStream_t stream) {
    const float* x     = (const float*)d_in[0];
    const float* pos   = (const float*)d_in[1];
    // d_in[2] = batch (unused: points are sorted, b = idx >> 10)
    const float* W1    = (const float*)d_in[3];
    const float* b1    = (const float*)d_in[4];
    const float* gamma = (const float*)d_in[5];
    const float* beta  = (const float*)d_in[6];
    const float* W2    = (const float*)d_in[7];
    const float* b2    = (const float*)d_in[8];
    float* out = (float*)d_out;
    char* ws = (char*)d_ws;
    int*   nbrs     = (int*)(ws + WS_NBRS);
    int*   nbr_cnt  = (int*)(ws + WS_NBRCNT);
    float* deg      = (float*)(ws + WS_DEG);
    float* stx      = (float*)(ws + WS_STX);
    float* sty      = (float*)(ws + WS_STY);
    float* defrep   = (float*)(ws + WS_DEFREP);
    float* scsh     = (float*)(ws + WS_SCSH);
    unsigned short* w2b = (unsigned short*)(ws + WS_W2B);
    float* partials = (float*)(ws + WS_PART);
    unsigned int* yb = (unsigned int*)(ws + WS_Y);
    float* bqpart   = (float*)(ws + WS_BQPART);

    k_prep<<<32, 256, 0, stream>>>(W2, w2b, defrep);
    k_ballquery<<<512, 256, 0, stream>>>(pos, nbrs, nbr_cnt, bqpart, defrep);
    k_nodeagg<<<128, 256, 0, stream>>>(bqpart, deg, stx, sty);
    k_y<<<256, 256, 0, stream>>>(x, W1, b1, pos, deg, stx, sty, yb, partials);
    k_finalize<<<1, 256, 0, stream>>>(gamma, beta, W1, partials, defrep, scsh);
    k_self<<<NPTS / 64, 256, 0, stream>>>(yb, scsh, w2b, b2, out);
    k_out<<<NPTS / 8, 256, 0, stream>>>(yb, pos, W1, scsh, w2b, b2, nbrs, nbr_cnt, out);
}